// Round 1
// baseline (273.939 us; speedup 1.0000x reference)
//
#include <hip/hip_runtime.h>
#include <math.h>

#define B_   128
#define A_   5
#define T_   50
#define HG_  19
#define WG_  19
#define NC_  80
#define HW_  (HG_*WG_)          // 361
#define NCELL (B_*A_*HW_)       // 231040
#define CSTRIDE 425             // channels per batch in input
#define EPS_ 1e-7f

__device__ __forceinline__ float softplusf(float x) {
    // log(1 + e^x), stable
    return (x > 0.f) ? (x + log1pf(expf(-x))) : log1pf(expf(x));
}

__constant__ float c_aw[A_] = {0.57273f, 1.87446f, 3.33843f, 7.88282f, 9.77052f};
__constant__ float c_ah[A_] = {0.677385f, 2.06253f, 5.47434f, 3.52778f, 9.16828f};

// ws layout (bytes):
//   0      : float accf[4]   {obj_sum, noobj_sum, cls_sum, box_sum}
//   16     : uint  acci[4]   {n_pos, n_mask, n_list, pad}
//   32     : uint  list[8192]
//   32800  : int4  meta[B_*T_]   {gi, gj, best|(valid<<8)|(ibits<<16), cid}
//   135200 : float4 tval[B_*T_]  {tx, ty, tw, th}
//   237600 : uchar mask[NCELL]
//   468640 : uchar noobj[NCELL]
//   total ~= 699680 bytes

// ---------------- K1: init + per-target encode + serial per-b scatter ----------
__global__ __launch_bounds__(64)
void k_encode(const float* __restrict__ tgt,
              float* accf, unsigned* acci,
              int4* __restrict__ meta, float4* __restrict__ tvalv,
              unsigned char* __restrict__ mask, unsigned char* __restrict__ noobj)
{
    const int b = blockIdx.x;
    const int lane = threadIdx.x;
    const int base = b * (A_ * HW_);

    // init this batch's cells
    for (int c = lane; c < A_ * HW_; c += 64) {
        mask[base + c]  = 0;
        noobj[base + c] = 1;
    }
    if (b == 0 && lane < 4) { accf[lane] = 0.f; acci[lane] = 0u; }

    __shared__ int4 smeta[T_];

    if (lane < T_) {
        const float* tp = tgt + (size_t)(b * T_ + lane) * 5;
        float t0 = tp[0], t1 = tp[1], t2 = tp[2], t3 = tp[3], t4 = tp[4];
        bool valid = (t0 + t1 + t2 + t3 + t4) > 0.f;
        float gx = t0 * WG_, gy = t1 * HG_, gw = t2 * WG_, gh = t3 * HG_;
        int gi = (int)gx; gi = min(max(gi, 0), WG_ - 1);
        int gj = (int)gy; gj = min(max(gj, 0), HG_ - 1);
        float area = gw * gh;
        float bestiou = -1.f; int best = 0; unsigned ibits = 0u;
        #pragma unroll
        for (int a = 0; a < A_; a++) {
            float inter = fminf(gw, c_aw[a]) * fminf(gh, c_ah[a]);
            float uni   = area + c_aw[a] * c_ah[a] - inter + 1e-16f;
            float iou   = inter / uni;
            if (iou > bestiou) { bestiou = iou; best = a; }   // first-index tie-break
            if (valid && iou > 0.5f) ibits |= (1u << a);
        }
        int cid = (int)t4; cid = min(max(cid, 0), NC_ - 1);
        int4 m;
        m.x = gi; m.y = gj;
        m.z = best | ((valid ? 1 : 0) << 8) | ((int)ibits << 16);
        m.w = cid;
        meta[b * T_ + lane] = m;
        float4 tv;
        tv.x = gx - (float)gi;
        tv.y = gy - (float)gj;
        tv.z = gw / c_aw[best];
        tv.w = gh / c_ah[best];
        tvalv[b * T_ + lane] = tv;
        smeta[lane] = m;
    }
    __syncthreads();

    // serial scatter (deterministic, matches numpy last/min/max semantics)
    if (lane == 0) {
        for (int t = 0; t < T_; t++) {
            int4 m = smeta[t];
            if (!((m.z >> 8) & 1)) continue;        // invalid -> dropped
            int gi = m.x, gj = m.y, best = m.z & 0xff;
            unsigned ibits = ((unsigned)m.z) >> 16;
            mask[base + (best * HG_ + gj) * WG_ + gi] = 1;
            #pragma unroll
            for (int a = 0; a < A_; a++)
                if (ibits & (1u << a))
                    noobj[base + (a * HG_ + gj) * WG_ + gi] = 0;
        }
    }
}

// ---------------- K2: conf channel over all cells + list build -----------------
__global__ __launch_bounds__(256)
void k_conf(const float* __restrict__ inp,
            float* accf, unsigned* acci, unsigned* __restrict__ list,
            const unsigned char* __restrict__ mask,
            const unsigned char* __restrict__ noobj)
{
    const int tid = threadIdx.x;
    const int idx = blockIdx.x * 256 + tid;
    float objv = 0.f, noobjv = 0.f; int mloc = 0;
    if (idx < NCELL) {
        int ba = idx / HW_;            // b*A + a
        int ji = idx - ba * HW_;
        int b  = ba / A_;
        int a  = ba - b * A_;
        float x = inp[(size_t)(b * CSTRIDE + a * 85 + 4) * HW_ + ji];
        int m  = mask[idx];
        int no = noobj[idx];
        float spx  = softplusf(x);       // -log(1 - sigmoid(x))
        float spnx = spx - x;            // -log(sigmoid(x))
        objv   = m  ? spnx : 1e-12f;     // bce(pconf*mask, mask)
        noobjv = no ? spx  : 1e-12f;     // bce(pconf*noobj, 0)
        mloc = m;
        if (m) {
            unsigned p = atomicAdd(&acci[2], 1u);
            list[p] = (unsigned)idx;
        }
    }
    __shared__ float sA[256], sB[256];
    __shared__ int   sC[256];
    sA[tid] = objv; sB[tid] = noobjv; sC[tid] = mloc;
    __syncthreads();
    for (int s = 128; s > 0; s >>= 1) {
        if (tid < s) { sA[tid] += sA[tid + s]; sB[tid] += sB[tid + s]; sC[tid] += sC[tid + s]; }
        __syncthreads();
    }
    if (tid == 0) {
        atomicAdd(&accf[0], sA[0]);
        atomicAdd(&accf[1], sB[0]);
        if (sC[0]) atomicAdd(&acci[1], (unsigned)sC[0]);
    }
}

// ---------------- K3: per-mask-cell class + box losses (1 wave / cell) ---------
__global__ __launch_bounds__(256)
void k_cells(const float* __restrict__ inp,
             const int4* __restrict__ meta, const float4* __restrict__ tvalv,
             float* accf, unsigned* acci, const unsigned* __restrict__ list)
{
    const int wave = threadIdx.x >> 6;
    const int lane = threadIdx.x & 63;
    const unsigned li = blockIdx.x * 4u + wave;
    const unsigned nl = acci[2];
    if (li >= nl) return;

    const int idx = (int)list[li];
    const int ba = idx / HW_;
    const int ji = idx - ba * HW_;
    const int b  = ba / A_;
    const int a  = ba - b * A_;

    // scan this batch's targets: lane t
    bool match = false;
    int4 m = make_int4(0, 0, 0, 0);
    if (lane < T_) {
        m = meta[b * T_ + lane];
        match = ((m.z >> 8) & 1) && ((m.z & 0xff) == a) && ((m.y * WG_ + m.x) == ji);
    }
    // tcls = union of one-hots over matching targets
    unsigned w0 = 0, w1 = 0, w2 = 0;
    if (match) {
        int c = m.w;
        if (c < 32)      w0 = 1u << c;
        else if (c < 64) w1 = 1u << (c - 32);
        else             w2 = 1u << (c - 64);
    }
    #pragma unroll
    for (int off = 32; off; off >>= 1) {
        w0 |= __shfl_xor(w0, off);
        w1 |= __shfl_xor(w1, off);
        w2 |= __shfl_xor(w2, off);
    }
    // tbox = last (highest t) matching target's tvals
    unsigned long long mm = __ballot(match);
    int tlast = 63 - __builtin_clzll(mm);              // mm != 0 guaranteed
    float4 tb = tvalv[b * T_ + tlast];                 // uniform addr -> broadcast

    const size_t base = (size_t)(b * CSTRIDE + a * 85) * HW_ + ji;
    float xa = inp[base + (size_t)lane * HW_];                         // channels 0..63
    float xb = (lane < 21) ? inp[base + (size_t)(64 + lane) * HW_] : 0.f; // 64..84

    // class loss: channels 5..84 -> classes 0..79
    float cls = 0.f;
    if (lane >= 5) {
        int c = lane - 5;                               // 0..58
        int t = ((c < 32 ? (w0 >> c) : (w1 >> (c - 32))) & 1);
        cls += softplusf(xa) - (float)t * xa;
    }
    if (lane < 21) {
        int c = 59 + lane;                              // 59..79
        int t = ((c < 64 ? (w1 >> (c - 32)) : (w2 >> (c - 64))) & 1);
        cls += softplusf(xb) - (float)t * xb;
    }
    #pragma unroll
    for (int off = 32; off; off >>= 1) cls += __shfl_xor(cls, off);

    // box: logits on lanes 0..3
    float x0 = __shfl(xa, 0), x1 = __shfl(xa, 1), x2 = __shfl(xa, 2), x3 = __shfl(xa, 3);
    if (lane == 0) {
        atomicAdd(&accf[2], cls);
        float px = 1.f / (1.f + expf(-x0));
        float py = 1.f / (1.f + expf(-x1));
        float pw = expf(x2);
        float ph = expf(x3);
        float b1x1 = px - pw * 0.5f, b1x2 = px + pw * 0.5f;
        float b1y1 = py - ph * 0.5f, b1y2 = py + ph * 0.5f;
        float b2x1 = tb.x - tb.z * 0.5f, b2x2 = tb.x + tb.z * 0.5f;
        float b2y1 = tb.y - tb.w * 0.5f, b2y2 = tb.y + tb.w * 0.5f;
        float iw = fmaxf(fminf(b1x2, b2x2) - fmaxf(b1x1, b2x1), 0.f);
        float ih = fmaxf(fminf(b1y2, b2y2) - fmaxf(b1y1, b2y1), 0.f);
        float inter = iw * ih;
        float uni = pw * ph + tb.z * tb.w - inter + EPS_;
        float iou = inter / uni;
        float cw = fmaxf(b1x2, b2x2) - fminf(b1x1, b2x1);
        float ch = fmaxf(b1y2, b2y2) - fminf(b1y1, b2y1);
        float c2 = cw * cw + ch * ch + EPS_;
        float rho2 = (tb.x - px) * (tb.x - px) + (tb.y - py) * (tb.y - py);
        float dv = atanf(tb.z / (tb.w + EPS_)) - atanf(pw / (ph + EPS_));
        float v = (4.f / (float)(M_PI * M_PI)) * dv * dv;
        float alpha = v / (v - iou + 1.f + EPS_);
        float ciou = iou - (rho2 / c2 + v * alpha);
        if (ciou > 0.f) {
            atomicAdd(&accf[3], 1.f - ciou);
            atomicAdd(&acci[0], 1u);
        }
    }
}

// ---------------- K4: finalize --------------------------------------------------
__global__ __launch_bounds__(64)
void k_final(const float* accf, const unsigned* acci, float* out)
{
    if (threadIdx.x == 0 && blockIdx.x == 0) {
        const float N = (float)NCELL;
        float box = 0.05f * accf[3] / fmaxf((float)acci[0], 1.f);
        float obj = 10.f  * accf[0] / N;
        float noo = 1.f   * accf[1] / N;
        float cls = 1.f   * accf[2] / fmaxf((float)acci[1] * (float)NC_, 1.f);
        out[0] = (box + obj + noo + cls) * (float)B_;
    }
}

extern "C" void kernel_launch(void* const* d_in, const int* in_sizes, int n_in,
                              void* d_out, int out_size, void* d_ws, size_t ws_size,
                              hipStream_t stream)
{
    const float* inp = (const float*)d_in[0];   // (128, 425, 19, 19) f32
    const float* tgt = (const float*)d_in[1];   // (128, 50, 5) f32
    float* out = (float*)d_out;

    char* w = (char*)d_ws;
    float*    accf  = (float*)(w + 0);
    unsigned* acci  = (unsigned*)(w + 16);
    unsigned* list  = (unsigned*)(w + 32);
    int4*     meta  = (int4*)(w + 32800);
    float4*   tvalv = (float4*)(w + 135200);
    unsigned char* mask  = (unsigned char*)(w + 237600);
    unsigned char* noobj = (unsigned char*)(w + 468640);

    k_encode<<<B_, 64, 0, stream>>>(tgt, accf, acci, meta, tvalv, mask, noobj);
    k_conf<<<(NCELL + 255) / 256, 256, 0, stream>>>(inp, accf, acci, list, mask, noobj);
    k_cells<<<(B_ * T_ + 3) / 4, 256, 0, stream>>>(inp, meta, tvalv, accf, acci, list);
    k_final<<<1, 64, 0, stream>>>(accf, acci, out);
}

// Round 2
// 50.058 us; speedup vs baseline: 5.4725x; 5.4725x over previous
//
#include <hip/hip_runtime.h>
#include <math.h>

#define B_   128
#define A_   5
#define T_   50
#define HG_  19
#define WG_  19
#define NC_  80
#define HW_  (HG_*WG_)          // 361
#define NCELL (B_*A_*HW_)       // 231040
#define CSTRIDE 425             // channels per batch in input
#define EPS_ 1e-7f
#define NCONFBLK ((NCELL + 255) / 256)   // 903
#define NCELLBLK 1600                    // 6400 waves / 4

__device__ __forceinline__ float softplusf(float x) {
    return (x > 0.f) ? (x + log1pf(expf(-x))) : log1pf(expf(x));
}

__constant__ float c_aw[A_] = {0.57273f, 1.87446f, 3.33843f, 7.88282f, 9.77052f};
__constant__ float c_ah[A_] = {0.677385f, 2.06253f, 5.47434f, 3.52778f, 9.16828f};

// ws layout (bytes):
//   0      : uint   nlist[128]                 (512)
//   512    : uint   blist[128*64]              (32768)   local cell idx per batch
//   33280  : int4   meta[6400]                 (102400)  {gi, gj, best|valid<<8|ibits<<16, cid}
//   135680 : float4 tval[6400]                 (102400)
//   238080 : uchar  flags[NCELL]               (231040)  bit0=mask, bit1=noobj
//   469120 : float2 confpart[903]              (7224)    {obj, noobj} per block
//   476352 : float4 cellpart[1600]             (25600)   {cls, box, npos, 0} per block
//   total ~= 502 KB

// ---------------- K1: init + per-target encode + serial per-b scatter + list ---
__global__ __launch_bounds__(64)
void k_encode(const float* __restrict__ tgt,
              unsigned* __restrict__ nlist, unsigned* __restrict__ blist,
              int4* __restrict__ meta, float4* __restrict__ tvalv,
              unsigned char* __restrict__ flags)
{
    const int b = blockIdx.x;
    const int lane = threadIdx.x;
    const int base = b * (A_ * HW_);

    for (int c = lane; c < A_ * HW_; c += 64)
        flags[base + c] = 2;                 // noobj=1, mask=0

    __shared__ int4 smeta[T_];

    if (lane < T_) {
        const float* tp = tgt + (size_t)(b * T_ + lane) * 5;
        float t0 = tp[0], t1 = tp[1], t2 = tp[2], t3 = tp[3], t4 = tp[4];
        bool valid = (t0 + t1 + t2 + t3 + t4) > 0.f;
        float gx = t0 * WG_, gy = t1 * HG_, gw = t2 * WG_, gh = t3 * HG_;
        int gi = (int)gx; gi = min(max(gi, 0), WG_ - 1);
        int gj = (int)gy; gj = min(max(gj, 0), HG_ - 1);
        float area = gw * gh;
        float bestiou = -1.f; int best = 0; unsigned ibits = 0u;
        #pragma unroll
        for (int a = 0; a < A_; a++) {
            float inter = fminf(gw, c_aw[a]) * fminf(gh, c_ah[a]);
            float uni   = area + c_aw[a] * c_ah[a] - inter + 1e-16f;
            float iou   = inter / uni;
            if (iou > bestiou) { bestiou = iou; best = a; }   // first-index tie-break
            if (valid && iou > 0.5f) ibits |= (1u << a);
        }
        int cid = (int)t4; cid = min(max(cid, 0), NC_ - 1);
        int4 m;
        m.x = gi; m.y = gj;
        m.z = best | ((valid ? 1 : 0) << 8) | ((int)ibits << 16);
        m.w = cid;
        meta[b * T_ + lane] = m;
        float4 tv;
        tv.x = gx - (float)gi;
        tv.y = gy - (float)gj;
        tv.z = gw / c_aw[best];
        tv.w = gh / c_ah[best];
        tvalv[b * T_ + lane] = tv;
        smeta[lane] = m;
    }
    __syncthreads();

    // deterministic serial scatter + dedup'd mask-cell list
    if (lane == 0) {
        int cnt = 0;
        for (int t = 0; t < T_; t++) {
            int4 m = smeta[t];
            if (!((m.z >> 8) & 1)) continue;            // invalid -> dropped
            int gi = m.x, gj = m.y, best = m.z & 0xff;
            unsigned ibits = ((unsigned)m.z) >> 16;
            int mcell = (best * HG_ + gj) * WG_ + gi;   // local within batch
            unsigned char f = flags[base + mcell];
            if (!(f & 1)) {                              // first time: append
                blist[b * 64 + cnt] = (unsigned)mcell;
                cnt++;
            }
            flags[base + mcell] = f | 1;
            #pragma unroll
            for (int a = 0; a < A_; a++)
                if (ibits & (1u << a)) {
                    int c = (a * HG_ + gj) * WG_ + gi;
                    flags[base + c] &= ~2;
                }
        }
        nlist[b] = (unsigned)cnt;
    }
}

// ---------------- K2: conf channel over all cells, per-block partials ----------
__global__ __launch_bounds__(256)
void k_conf(const float* __restrict__ inp,
            const unsigned char* __restrict__ flags,
            float2* __restrict__ confpart)
{
    const int tid = threadIdx.x;
    const int idx = blockIdx.x * 256 + tid;
    float objv = 0.f, noobjv = 0.f;
    if (idx < NCELL) {
        int ba = idx / HW_;            // b*A + a
        int ji = idx - ba * HW_;
        int b  = ba / A_;
        int a  = ba - b * A_;
        float x = inp[(size_t)(b * CSTRIDE + a * 85 + 4) * HW_ + ji];
        unsigned char f = flags[idx];
        float spx  = softplusf(x);       // -log(1 - sigmoid(x))
        float spnx = spx - x;            // -log(sigmoid(x))
        objv   = (f & 1) ? spnx : 1e-12f;
        noobjv = (f & 2) ? spx  : 1e-12f;
    }
    __shared__ float sA[256], sB[256];
    sA[tid] = objv; sB[tid] = noobjv;
    __syncthreads();
    for (int s = 128; s > 0; s >>= 1) {
        if (tid < s) { sA[tid] += sA[tid + s]; sB[tid] += sB[tid + s]; }
        __syncthreads();
    }
    if (tid == 0) confpart[blockIdx.x] = make_float2(sA[0], sB[0]);
}

// ---------------- K3: per-mask-cell class + box losses (1 wave / cell) ---------
__global__ __launch_bounds__(256)
void k_cells(const float* __restrict__ inp,
             const int4* __restrict__ meta, const float4* __restrict__ tvalv,
             const unsigned* __restrict__ nlist, const unsigned* __restrict__ blist,
             float4* __restrict__ cellpart)
{
    const int wave = threadIdx.x >> 6;
    const int lane = threadIdx.x & 63;
    const int li = blockIdx.x * 4 + wave;        // 0..6399
    const int b  = li / T_;
    const int k  = li - b * T_;

    float clsv = 0.f, boxv = 0.f, posf = 0.f;

    if ((unsigned)k < nlist[b]) {
        const int cell = (int)blist[b * 64 + k]; // a*361 + ji
        const int a  = cell / HW_;
        const int ji = cell - a * HW_;

        bool match = false;
        int4 m = make_int4(0, 0, 0, 0);
        if (lane < T_) {
            m = meta[b * T_ + lane];
            match = ((m.z >> 8) & 1) && ((m.z & 0xff) == a) && ((m.y * WG_ + m.x) == ji);
        }
        unsigned w0 = 0, w1 = 0, w2 = 0;
        if (match) {
            int c = m.w;
            if (c < 32)      w0 = 1u << c;
            else if (c < 64) w1 = 1u << (c - 32);
            else             w2 = 1u << (c - 64);
        }
        #pragma unroll
        for (int off = 32; off; off >>= 1) {
            w0 |= __shfl_xor(w0, off);
            w1 |= __shfl_xor(w1, off);
            w2 |= __shfl_xor(w2, off);
        }
        unsigned long long mm = __ballot(match);
        int tlast = 63 - __builtin_clzll(mm);
        float4 tb = tvalv[b * T_ + tlast];

        const size_t base = (size_t)(b * CSTRIDE + a * 85) * HW_ + ji;
        float xa = inp[base + (size_t)lane * HW_];
        float xb = (lane < 21) ? inp[base + (size_t)(64 + lane) * HW_] : 0.f;

        float cls = 0.f;
        if (lane >= 5) {
            int c = lane - 5;                               // 0..58
            int t = ((c < 32 ? (w0 >> c) : (w1 >> (c - 32))) & 1);
            cls += softplusf(xa) - (float)t * xa;
        }
        if (lane < 21) {
            int c = 59 + lane;                              // 59..79
            int t = ((c < 64 ? (w1 >> (c - 32)) : (w2 >> (c - 64))) & 1);
            cls += softplusf(xb) - (float)t * xb;
        }
        #pragma unroll
        for (int off = 32; off; off >>= 1) cls += __shfl_xor(cls, off);

        float x0 = __shfl(xa, 0), x1 = __shfl(xa, 1), x2 = __shfl(xa, 2), x3 = __shfl(xa, 3);
        if (lane == 0) {
            clsv = cls;
            float px = 1.f / (1.f + expf(-x0));
            float py = 1.f / (1.f + expf(-x1));
            float pw = expf(x2);
            float ph = expf(x3);
            float b1x1 = px - pw * 0.5f, b1x2 = px + pw * 0.5f;
            float b1y1 = py - ph * 0.5f, b1y2 = py + ph * 0.5f;
            float b2x1 = tb.x - tb.z * 0.5f, b2x2 = tb.x + tb.z * 0.5f;
            float b2y1 = tb.y - tb.w * 0.5f, b2y2 = tb.y + tb.w * 0.5f;
            float iw = fmaxf(fminf(b1x2, b2x2) - fmaxf(b1x1, b2x1), 0.f);
            float ih = fmaxf(fminf(b1y2, b2y2) - fmaxf(b1y1, b2y1), 0.f);
            float inter = iw * ih;
            float uni = pw * ph + tb.z * tb.w - inter + EPS_;
            float iou = inter / uni;
            float cw = fmaxf(b1x2, b2x2) - fminf(b1x1, b2x1);
            float ch = fmaxf(b1y2, b2y2) - fminf(b1y1, b2y1);
            float c2 = cw * cw + ch * ch + EPS_;
            float rho2 = (tb.x - px) * (tb.x - px) + (tb.y - py) * (tb.y - py);
            float dv = atanf(tb.z / (tb.w + EPS_)) - atanf(pw / (ph + EPS_));
            float v = (4.f / (float)(M_PI * M_PI)) * dv * dv;
            float alpha = v / (v - iou + 1.f + EPS_);
            float ciou = iou - (rho2 / c2 + v * alpha);
            if (ciou > 0.f) { boxv = 1.f - ciou; posf = 1.f; }
        }
    }

    __shared__ float sc[4], sb[4], sp[4];
    if (lane == 0) { sc[wave] = clsv; sb[wave] = boxv; sp[wave] = posf; }
    __syncthreads();
    if (threadIdx.x == 0) {
        cellpart[blockIdx.x] = make_float4(sc[0] + sc[1] + sc[2] + sc[3],
                                           sb[0] + sb[1] + sb[2] + sb[3],
                                           sp[0] + sp[1] + sp[2] + sp[3], 0.f);
    }
}

// ---------------- K4: final reduction ------------------------------------------
__global__ __launch_bounds__(256)
void k_final(const float2* __restrict__ confpart,
             const float4* __restrict__ cellpart,
             const unsigned* __restrict__ nlist,
             float* __restrict__ out)
{
    const int tid = threadIdx.x;
    float obj = 0.f, noo = 0.f, cls = 0.f, box = 0.f, npos = 0.f, nmask = 0.f;
    for (int i = tid; i < NCONFBLK; i += 256) {
        float2 c = confpart[i];
        obj += c.x; noo += c.y;
    }
    for (int i = tid; i < NCELLBLK; i += 256) {
        float4 c = cellpart[i];
        cls += c.x; box += c.y; npos += c.z;
    }
    if (tid < B_) nmask = (float)nlist[tid];

    __shared__ float s[6][256];
    s[0][tid] = obj; s[1][tid] = noo; s[2][tid] = cls;
    s[3][tid] = box; s[4][tid] = npos; s[5][tid] = nmask;
    __syncthreads();
    for (int st = 128; st > 0; st >>= 1) {
        if (tid < st)
            #pragma unroll
            for (int j = 0; j < 6; j++) s[j][tid] += s[j][tid + st];
        __syncthreads();
    }
    if (tid == 0) {
        const float N = (float)NCELL;
        float box_l = 0.05f * s[3][0] / fmaxf(s[4][0], 1.f);
        float obj_l = 10.f  * s[0][0] / N;
        float noo_l = 1.f   * s[1][0] / N;
        float cls_l = 1.f   * s[2][0] / fmaxf(s[5][0] * (float)NC_, 1.f);
        out[0] = (box_l + obj_l + noo_l + cls_l) * (float)B_;
    }
}

extern "C" void kernel_launch(void* const* d_in, const int* in_sizes, int n_in,
                              void* d_out, int out_size, void* d_ws, size_t ws_size,
                              hipStream_t stream)
{
    const float* inp = (const float*)d_in[0];   // (128, 425, 19, 19) f32
    const float* tgt = (const float*)d_in[1];   // (128, 50, 5) f32
    float* out = (float*)d_out;

    char* w = (char*)d_ws;
    unsigned* nlist = (unsigned*)(w + 0);
    unsigned* blist = (unsigned*)(w + 512);
    int4*     meta  = (int4*)(w + 33280);
    float4*   tvalv = (float4*)(w + 135680);
    unsigned char* flags = (unsigned char*)(w + 238080);
    float2*   confpart = (float2*)(w + 469120);
    float4*   cellpart = (float4*)(w + 476352);

    k_encode<<<B_, 64, 0, stream>>>(tgt, nlist, blist, meta, tvalv, flags);
    k_conf<<<NCONFBLK, 256, 0, stream>>>(inp, flags, confpart);
    k_cells<<<NCELLBLK, 256, 0, stream>>>(inp, meta, tvalv, nlist, blist, cellpart);
    k_final<<<1, 256, 0, stream>>>(confpart, cellpart, nlist, out);
}

// Round 3
// 34.747 us; speedup vs baseline: 7.8837x; 1.4406x over previous
//
#include <hip/hip_runtime.h>
#include <math.h>

#define B_   128
#define A_   5
#define T_   50
#define HG_  19
#define WG_  19
#define NC_  80
#define HW_  361                 // HG_*WG_
#define AHW  (A_*HW_)            // 1805
#define NCELL (B_*A_*HW_)        // 231040
#define CSTRIDE 425              // channels per batch in input
#define EPS_ 1e-7f
#define NW   16                  // waves per block
#define NTHR 1024

__device__ __forceinline__ float softplusf(float x) {
    return (x > 0.f) ? (x + log1pf(expf(-x))) : log1pf(expf(x));
}

__constant__ float c_aw[A_] = {0.57273f, 1.87446f, 3.33843f, 7.88282f, 9.77052f};
__constant__ float c_ah[A_] = {0.677385f, 2.06253f, 5.47434f, 3.52778f, 9.16828f};

// ws layout: float part[B_][8] = {obj, noobj, cls, box, npos, nmask, 0, 0}

// ---------------- K1: fully fused per-batch loss ------------------------------
__global__ __launch_bounds__(NTHR)
void k_batch(const float* __restrict__ inp, const float* __restrict__ tgt,
             float* __restrict__ part)
{
    const int b    = blockIdx.x;
    const int tid  = threadIdx.x;
    const int lane = tid & 63;
    const int wav  = tid >> 6;

    __shared__ unsigned maskbits[57], ignbits[57];   // 1805 bits each
    __shared__ int    skey[T_];                      // cell idx (a*361+ji) or -1
    __shared__ float4 stval[T_];
    __shared__ int    scid[T_];
    __shared__ uint4  sclsb[T_];                     // {w0,w1,w2, owner}
    __shared__ float  sobj[NW], snoo[NW], scls[NW], sbox[NW], spos[NW];
    __shared__ int    snmask;

    if (tid < 57) { maskbits[tid] = 0u; ignbits[tid] = 0u; }
    if (tid == 0) snmask = 0;
    __syncthreads();

    // ---- phase 1: per-target encode (wave 0, lanes 0..49), parallel scatter --
    if (tid < T_) {
        const float* tp = tgt + (size_t)(b * T_ + tid) * 5;
        float t0 = tp[0], t1 = tp[1], t2 = tp[2], t3 = tp[3], t4 = tp[4];
        bool valid = (t0 + t1 + t2 + t3 + t4) > 0.f;
        float gx = t0 * WG_, gy = t1 * HG_, gw = t2 * WG_, gh = t3 * HG_;
        int gi = (int)gx; gi = min(max(gi, 0), WG_ - 1);
        int gj = (int)gy; gj = min(max(gj, 0), HG_ - 1);
        float area = gw * gh;
        float bestiou = -1.f; int best = 0; unsigned ibits = 0u;
        #pragma unroll
        for (int a = 0; a < A_; a++) {
            float inter = fminf(gw, c_aw[a]) * fminf(gh, c_ah[a]);
            float uni   = area + c_aw[a] * c_ah[a] - inter + 1e-16f;
            float iou   = inter / uni;
            if (iou > bestiou) { bestiou = iou; best = a; }   // first-index tie
            if (valid && iou > 0.5f) ibits |= (1u << a);
        }
        int cid = (int)t4; cid = min(max(cid, 0), NC_ - 1);
        int key = (best * HG_ + gj) * WG_ + gi;
        skey[tid] = valid ? key : -1;
        scid[tid] = cid;
        float4 tv;
        tv.x = gx - (float)gi;
        tv.y = gy - (float)gj;
        tv.z = gw / c_aw[best];
        tv.w = gh / c_ah[best];
        stval[tid] = tv;
        if (valid) {
            atomicOr(&maskbits[key >> 5], 1u << (key & 31));
            #pragma unroll
            for (int a = 0; a < A_; a++)
                if (ibits & (1u << a)) {
                    int c = (a * HG_ + gj) * WG_ + gi;
                    atomicOr(&ignbits[c >> 5], 1u << (c & 31));
                }
        }
    }
    __syncthreads();

    // ---- phase 1.5: owner (= highest-t target of its cell) + class-bit union -
    bool owner = false;
    if (tid < T_) {
        int mykey = skey[tid];
        if (mykey >= 0) {
            owner = true;
            unsigned w0 = 0, w1 = 0, w2 = 0;
            for (int t2 = 0; t2 < T_; t2++) {
                if (skey[t2] == mykey) {
                    if (t2 > tid) owner = false;   // a later target owns this cell
                    int c = scid[t2];
                    if (c < 32)      w0 |= 1u << c;
                    else if (c < 64) w1 |= 1u << (c - 32);
                    else             w2 |= 1u << (c - 64);
                }
            }
            sclsb[tid] = make_uint4(w0, w1, w2, owner ? 1u : 0u);
        } else {
            sclsb[tid] = make_uint4(0u, 0u, 0u, 0u);
        }
    }
    if (wav == 0) {
        unsigned long long om = __ballot(owner);
        if (lane == 0) snmask = __popcll(om);
    }
    __syncthreads();

    // ---- phase 2: conf channel over this batch's 1805 cells ------------------
    float objv = 0.f, noov = 0.f;
    for (int c = tid; c < AHW; c += NTHR) {
        int a  = c / HW_;
        int ji = c - a * HW_;
        float x = inp[(size_t)(b * CSTRIDE + a * 85 + 4) * HW_ + ji];
        bool mk = (maskbits[c >> 5] >> (c & 31)) & 1;
        bool ig = (ignbits[c >> 5]  >> (c & 31)) & 1;
        float spx = softplusf(x);                 // -log(1 - sigmoid(x))
        objv += mk ? (spx - x) : 1e-12f;          // bce(pconf*mask, mask)
        noov += ig ? 1e-12f : spx;                // bce(pconf*noobj, 0)
    }

    // ---- phase 3: owner cells -> class + box losses (1 wave per cell) --------
    float clsv = 0.f, boxv = 0.f, posv = 0.f;
    for (int t = wav; t < T_; t += NW) {
        uint4 cb = sclsb[t];
        if (!cb.w) continue;                       // invalid or non-owner
        int key = skey[t];
        int a   = key / HW_;
        int ji  = key - a * HW_;
        float4 tb = stval[t];                      // owner == last writer -> tbox

        const size_t base = (size_t)(b * CSTRIDE + a * 85) * HW_ + ji;
        float xa = inp[base + (size_t)lane * HW_];                           // ch 0..63
        float xb = (lane < 21) ? inp[base + (size_t)(64 + lane) * HW_] : 0.f; // ch 64..84

        float cls = 0.f;
        if (lane >= 5) {
            int c = lane - 5;                      // classes 0..58
            int tt = ((c < 32 ? (cb.x >> c) : (cb.y >> (c - 32))) & 1);
            cls += softplusf(xa) - (float)tt * xa;
        }
        if (lane < 21) {
            int c = 59 + lane;                     // classes 59..79
            int tt = ((c < 64 ? (cb.y >> (c - 32)) : (cb.z >> (c - 64))) & 1);
            cls += softplusf(xb) - (float)tt * xb;
        }
        #pragma unroll
        for (int off = 32; off; off >>= 1) cls += __shfl_xor(cls, off);

        float x0 = __shfl(xa, 0), x1 = __shfl(xa, 1), x2 = __shfl(xa, 2), x3 = __shfl(xa, 3);
        if (lane == 0) {
            clsv += cls;
            float px = 1.f / (1.f + expf(-x0));
            float py = 1.f / (1.f + expf(-x1));
            float pw = expf(x2);
            float ph = expf(x3);
            float b1x1 = px - pw * 0.5f, b1x2 = px + pw * 0.5f;
            float b1y1 = py - ph * 0.5f, b1y2 = py + ph * 0.5f;
            float b2x1 = tb.x - tb.z * 0.5f, b2x2 = tb.x + tb.z * 0.5f;
            float b2y1 = tb.y - tb.w * 0.5f, b2y2 = tb.y + tb.w * 0.5f;
            float iw = fmaxf(fminf(b1x2, b2x2) - fmaxf(b1x1, b2x1), 0.f);
            float ih = fmaxf(fminf(b1y2, b2y2) - fmaxf(b1y1, b2y1), 0.f);
            float inter = iw * ih;
            float uni = pw * ph + tb.z * tb.w - inter + EPS_;
            float iou = inter / uni;
            float cw = fmaxf(b1x2, b2x2) - fminf(b1x1, b2x1);
            float ch = fmaxf(b1y2, b2y2) - fminf(b1y1, b2y1);
            float c2 = cw * cw + ch * ch + EPS_;
            float rho2 = (tb.x - px) * (tb.x - px) + (tb.y - py) * (tb.y - py);
            float dv = atanf(tb.z / (tb.w + EPS_)) - atanf(pw / (ph + EPS_));
            float v = (4.f / (float)(M_PI * M_PI)) * dv * dv;
            float alpha = v / (v - iou + 1.f + EPS_);
            float ciou = iou - (rho2 / c2 + v * alpha);
            if (ciou > 0.f) { boxv += 1.f - ciou; posv += 1.f; }
        }
    }

    // ---- block reduction -----------------------------------------------------
    #pragma unroll
    for (int off = 32; off; off >>= 1) {
        objv += __shfl_xor(objv, off);
        noov += __shfl_xor(noov, off);
    }
    if (lane == 0) { sobj[wav] = objv; snoo[wav] = noov;
                     scls[wav] = clsv; sbox[wav] = boxv; spos[wav] = posv; }
    __syncthreads();
    if (tid == 0) {
        float o = 0.f, n = 0.f, c = 0.f, bx = 0.f, p = 0.f;
        #pragma unroll
        for (int w = 0; w < NW; w++) {
            o += sobj[w]; n += snoo[w]; c += scls[w]; bx += sbox[w]; p += spos[w];
        }
        float* pr = part + b * 8;
        pr[0] = o; pr[1] = n; pr[2] = c; pr[3] = bx;
        pr[4] = p; pr[5] = (float)snmask; pr[6] = 0.f; pr[7] = 0.f;
    }
}

// ---------------- K2: final reduction over 128 batch partials ------------------
__global__ __launch_bounds__(128)
void k_final(const float* __restrict__ part, float* __restrict__ out)
{
    const int tid = threadIdx.x;
    __shared__ float s[6][128];
    const float* pr = part + tid * 8;
    #pragma unroll
    for (int j = 0; j < 6; j++) s[j][tid] = pr[j];
    __syncthreads();
    for (int st = 64; st > 0; st >>= 1) {
        if (tid < st)
            #pragma unroll
            for (int j = 0; j < 6; j++) s[j][tid] += s[j][tid + st];
        __syncthreads();
    }
    if (tid == 0) {
        const float N = (float)NCELL;
        float obj_l = 10.f  * s[0][0] / N;
        float noo_l = 1.f   * s[1][0] / N;
        float cls_l = 1.f   * s[2][0] / fmaxf(s[5][0] * (float)NC_, 1.f);
        float box_l = 0.05f * s[3][0] / fmaxf(s[4][0], 1.f);
        out[0] = (box_l + obj_l + noo_l + cls_l) * (float)B_;
    }
}

extern "C" void kernel_launch(void* const* d_in, const int* in_sizes, int n_in,
                              void* d_out, int out_size, void* d_ws, size_t ws_size,
                              hipStream_t stream)
{
    const float* inp = (const float*)d_in[0];   // (128, 425, 19, 19) f32
    const float* tgt = (const float*)d_in[1];   // (128, 50, 5) f32
    float* out = (float*)d_out;
    float* part = (float*)d_ws;                 // 128 * 8 floats

    k_batch<<<B_, NTHR, 0, stream>>>(inp, tgt, part);
    k_final<<<1, 128, 0, stream>>>(part, out);
}

// Round 4
// 27.116 us; speedup vs baseline: 10.1024x; 1.2814x over previous
//
#include <hip/hip_runtime.h>
#include <math.h>

#define B_   128
#define A_   5
#define T_   50
#define HG_  19
#define WG_  19
#define NC_  80
#define HW_  361                 // HG_*WG_
#define AHW  (A_*HW_)            // 1805
#define NCELL (B_*A_*HW_)        // 231040
#define CSTRIDE 425              // channels per batch in input
#define EPS_ 1e-7f
#define NW   16                  // waves per block
#define NTHR 1024
#define SUBS 4                   // blocks per batch
#define CPS  452                 // ceil(1805/4) conf cells per sub-block
#define NPART (B_*SUBS)          // 512 partial rows

__device__ __forceinline__ float softplusf(float x) {
    return (x > 0.f) ? (x + log1pf(expf(-x))) : log1pf(expf(x));
}

__constant__ float c_aw[A_] = {0.57273f, 1.87446f, 3.33843f, 7.88282f, 9.77052f};
__constant__ float c_ah[A_] = {0.677385f, 2.06253f, 5.47434f, 3.52778f, 9.16828f};

// ws layout: float part[NPART][8] = {obj, noobj, cls, box, npos, nmask, 0, 0}

// ---------------- K1: fused per-batch loss, 4 sub-blocks per batch ------------
__global__ __launch_bounds__(NTHR)
void k_batch(const float* __restrict__ inp, const float* __restrict__ tgt,
             float* __restrict__ part)
{
    const int b    = blockIdx.x >> 2;
    const int sub  = blockIdx.x & 3;
    const int tid  = threadIdx.x;
    const int lane = tid & 63;
    const int wav  = tid >> 6;

    __shared__ unsigned maskbits[57], ignbits[57];   // 1805 bits each
    __shared__ int    skey[T_];                      // cell idx (a*361+ji) or -1
    __shared__ float4 stval[T_];
    __shared__ int    scid[T_];
    __shared__ uint4  sclsb[T_];                     // {w0,w1,w2, owner}
    __shared__ float  sobj[NW], snoo[NW], scls[NW], sbox[NW], spos[NW];
    __shared__ int    snmask;

    if (tid < 57) { maskbits[tid] = 0u; ignbits[tid] = 0u; }
    if (tid == 0) snmask = 0;
    __syncthreads();

    // ---- phase 1: per-target encode (lanes 0..49 of wave 0) ------------------
    if (tid < T_) {
        const float* tp = tgt + (size_t)(b * T_ + tid) * 5;
        float t0 = tp[0], t1 = tp[1], t2 = tp[2], t3 = tp[3], t4 = tp[4];
        bool valid = (t0 + t1 + t2 + t3 + t4) > 0.f;
        float gx = t0 * WG_, gy = t1 * HG_, gw = t2 * WG_, gh = t3 * HG_;
        int gi = (int)gx; gi = min(max(gi, 0), WG_ - 1);
        int gj = (int)gy; gj = min(max(gj, 0), HG_ - 1);
        float area = gw * gh;
        float bestiou = -1.f; int best = 0; unsigned ibits = 0u;
        #pragma unroll
        for (int a = 0; a < A_; a++) {
            float inter = fminf(gw, c_aw[a]) * fminf(gh, c_ah[a]);
            float uni   = area + c_aw[a] * c_ah[a] - inter + 1e-16f;
            float iou   = inter / uni;
            if (iou > bestiou) { bestiou = iou; best = a; }   // first-index tie
            if (valid && iou > 0.5f) ibits |= (1u << a);
        }
        int cid = (int)t4; cid = min(max(cid, 0), NC_ - 1);
        int key = (best * HG_ + gj) * WG_ + gi;
        skey[tid] = valid ? key : -1;
        scid[tid] = cid;
        float4 tv;
        tv.x = gx - (float)gi;
        tv.y = gy - (float)gj;
        tv.z = gw / c_aw[best];
        tv.w = gh / c_ah[best];
        stval[tid] = tv;
        if (valid) {
            atomicOr(&maskbits[key >> 5], 1u << (key & 31));
            #pragma unroll
            for (int a = 0; a < A_; a++)
                if (ibits & (1u << a)) {
                    int c = (a * HG_ + gj) * WG_ + gi;
                    atomicOr(&ignbits[c >> 5], 1u << (c & 31));
                }
        }
    }
    __syncthreads();

    // ---- phase 1.5: owner (= highest-t target of its cell) + class-bit union -
    bool owner = false;
    if (tid < T_) {
        int mykey = skey[tid];
        if (mykey >= 0) {
            owner = true;
            unsigned w0 = 0, w1 = 0, w2 = 0;
            for (int t2 = 0; t2 < T_; t2++) {
                if (skey[t2] == mykey) {
                    if (t2 > tid) owner = false;   // later target owns this cell
                    int c = scid[t2];
                    if (c < 32)      w0 |= 1u << c;
                    else if (c < 64) w1 |= 1u << (c - 32);
                    else             w2 |= 1u << (c - 64);
                }
            }
            sclsb[tid] = make_uint4(w0, w1, w2, owner ? 1u : 0u);
        } else {
            sclsb[tid] = make_uint4(0u, 0u, 0u, 0u);
        }
    }
    if (wav == 0) {
        unsigned long long om = __ballot(owner);
        if (lane == 0 && sub == 0) snmask = __popcll(om);
    }
    __syncthreads();

    // ---- phase 2: conf channel, contiguous 452-cell slice per sub-block ------
    float objv = 0.f, noov = 0.f;
    {
        int c = sub * CPS + tid;
        if (tid < CPS && c < AHW) {
            int a  = c / HW_;
            int ji = c - a * HW_;
            float x = inp[(size_t)(b * CSTRIDE + a * 85 + 4) * HW_ + ji];
            bool mk = (maskbits[c >> 5] >> (c & 31)) & 1;
            bool ig = (ignbits[c >> 5]  >> (c & 31)) & 1;
            float spx = softplusf(x);                 // -log(1 - sigmoid(x))
            objv = mk ? (spx - x) : 1e-12f;
            noov = ig ? 1e-12f : spx;
        }
    }

    // ---- phase 3: owner cells, one per wave (t = 4*wav + sub) ----------------
    float clsv = 0.f, boxv = 0.f, posv = 0.f;
    {
        const int t = 4 * wav + sub;                 // 0..63 covers 0..49
        uint4 cb = (t < T_) ? sclsb[t] : make_uint4(0u, 0u, 0u, 0u);
        if (cb.w) {
            int key = skey[t];
            int a   = key / HW_;
            int ji  = key - a * HW_;
            float4 tb = stval[t];                    // owner == last writer

            const size_t base = (size_t)(b * CSTRIDE + a * 85) * HW_ + ji;
            float xa = inp[base + (size_t)lane * HW_];                            // ch 0..63
            float xb = (lane < 21) ? inp[base + (size_t)(64 + lane) * HW_] : 0.f; // ch 64..84

            float cls = 0.f;
            if (lane >= 5) {
                int c = lane - 5;                    // classes 0..58
                int tt = ((c < 32 ? (cb.x >> c) : (cb.y >> (c - 32))) & 1);
                cls += softplusf(xa) - (float)tt * xa;
            }
            if (lane < 21) {
                int c = 59 + lane;                   // classes 59..79
                int tt = ((c < 64 ? (cb.y >> (c - 32)) : (cb.z >> (c - 64))) & 1);
                cls += softplusf(xb) - (float)tt * xb;
            }
            #pragma unroll
            for (int off = 32; off; off >>= 1) cls += __shfl_xor(cls, off);

            float x0 = __shfl(xa, 0), x1 = __shfl(xa, 1);
            float x2 = __shfl(xa, 2), x3 = __shfl(xa, 3);
            if (lane == 0) {
                clsv = cls;
                float px = 1.f / (1.f + expf(-x0));
                float py = 1.f / (1.f + expf(-x1));
                float pw = expf(x2);
                float ph = expf(x3);
                float b1x1 = px - pw * 0.5f, b1x2 = px + pw * 0.5f;
                float b1y1 = py - ph * 0.5f, b1y2 = py + ph * 0.5f;
                float b2x1 = tb.x - tb.z * 0.5f, b2x2 = tb.x + tb.z * 0.5f;
                float b2y1 = tb.y - tb.w * 0.5f, b2y2 = tb.y + tb.w * 0.5f;
                float iw = fmaxf(fminf(b1x2, b2x2) - fmaxf(b1x1, b2x1), 0.f);
                float ih = fmaxf(fminf(b1y2, b2y2) - fmaxf(b1y1, b2y1), 0.f);
                float inter = iw * ih;
                float uni = pw * ph + tb.z * tb.w - inter + EPS_;
                float iou = inter / uni;
                float cw = fmaxf(b1x2, b2x2) - fminf(b1x1, b2x1);
                float ch = fmaxf(b1y2, b2y2) - fminf(b1y1, b2y1);
                float c2 = cw * cw + ch * ch + EPS_;
                float rho2 = (tb.x - px) * (tb.x - px) + (tb.y - py) * (tb.y - py);
                float dv = atanf(tb.z / (tb.w + EPS_)) - atanf(pw / (ph + EPS_));
                float v = (4.f / (float)(M_PI * M_PI)) * dv * dv;
                float alpha = v / (v - iou + 1.f + EPS_);
                float ciou = iou - (rho2 / c2 + v * alpha);
                if (ciou > 0.f) { boxv = 1.f - ciou; posv = 1.f; }
            }
        }
    }

    // ---- block reduction -----------------------------------------------------
    #pragma unroll
    for (int off = 32; off; off >>= 1) {
        objv += __shfl_xor(objv, off);
        noov += __shfl_xor(noov, off);
    }
    if (lane == 0) { sobj[wav] = objv; snoo[wav] = noov;
                     scls[wav] = clsv; sbox[wav] = boxv; spos[wav] = posv; }
    __syncthreads();
    if (tid == 0) {
        float o = 0.f, n = 0.f, c = 0.f, bx = 0.f, p = 0.f;
        #pragma unroll
        for (int w = 0; w < NW; w++) {
            o += sobj[w]; n += snoo[w]; c += scls[w]; bx += sbox[w]; p += spos[w];
        }
        float* pr = part + (size_t)blockIdx.x * 8;
        pr[0] = o; pr[1] = n; pr[2] = c; pr[3] = bx;
        pr[4] = p; pr[5] = (float)snmask; pr[6] = 0.f; pr[7] = 0.f;
    }
}

// ---------------- K2: final reduction over 512 partials ------------------------
__global__ __launch_bounds__(256)
void k_final(const float* __restrict__ part, float* __restrict__ out)
{
    const int tid = threadIdx.x;
    __shared__ float s[6][256];
    float v[6] = {0.f, 0.f, 0.f, 0.f, 0.f, 0.f};
    for (int i = tid; i < NPART; i += 256) {
        const float* pr = part + (size_t)i * 8;
        #pragma unroll
        for (int j = 0; j < 6; j++) v[j] += pr[j];
    }
    #pragma unroll
    for (int j = 0; j < 6; j++) s[j][tid] = v[j];
    __syncthreads();
    for (int st = 128; st > 0; st >>= 1) {
        if (tid < st)
            #pragma unroll
            for (int j = 0; j < 6; j++) s[j][tid] += s[j][tid + st];
        __syncthreads();
    }
    if (tid == 0) {
        const float N = (float)NCELL;
        float obj_l = 10.f  * s[0][0] / N;
        float noo_l = 1.f   * s[1][0] / N;
        float cls_l = 1.f   * s[2][0] / fmaxf(s[5][0] * (float)NC_, 1.f);
        float box_l = 0.05f * s[3][0] / fmaxf(s[4][0], 1.f);
        out[0] = (box_l + obj_l + noo_l + cls_l) * (float)B_;
    }
}

extern "C" void kernel_launch(void* const* d_in, const int* in_sizes, int n_in,
                              void* d_out, int out_size, void* d_ws, size_t ws_size,
                              hipStream_t stream)
{
    const float* inp = (const float*)d_in[0];   // (128, 425, 19, 19) f32
    const float* tgt = (const float*)d_in[1];   // (128, 50, 5) f32
    float* out = (float*)d_out;
    float* part = (float*)d_ws;                 // NPART * 8 floats

    k_batch<<<B_ * SUBS, NTHR, 0, stream>>>(inp, tgt, part);
    k_final<<<1, 256, 0, stream>>>(part, out);
}